// Round 1
// baseline (5876.039 us; speedup 1.0000x reference)
//
#include <hip/hip_runtime.h>
#include <math.h>

// TTT recurrence: one wave (64 lanes) per batch row, lane = hidden index.
// W2 kept twice in registers (row-major for fwd + rank-1 update, col-major for
// bwd) to avoid cross-lane transposes. h1/dz2 broadcast via LDS float4 reads
// (uniform address -> bank broadcast, conflict-free).

#define TT  784
#define HH  64
#define LR  0.01f
#define NGS 4

__global__ __launch_bounds__(64)
void ttt_kernel(const float* __restrict__ ts,
                const float* __restrict__ xs,
                const int*   __restrict__ mask,
                const float* __restrict__ W1,
                const float* __restrict__ b1,
                const float* __restrict__ W2,
                const float* __restrict__ b2,
                const float* __restrict__ W3,
                const float* __restrict__ b3,
                float* __restrict__ out)
{
    __shared__ __align__(16) float s_h1[HH];
    __shared__ __align__(16) float s_dz2[HH];
    __shared__ float s_ts[TT];
    __shared__ float s_xs[TT];
    __shared__ int   s_mask[TT - 1];

    const int row  = blockIdx.x;
    const int lane = threadIdx.x;  // 0..63

    // Stage the row's sequence data into LDS (coalesced, one-time).
    for (int i = lane; i < TT; i += HH) {
        s_ts[i] = ts[i];
        s_xs[i] = xs[row * TT + i];
    }
    for (int i = lane; i < TT - 1; i += HH) s_mask[i] = mask[row * (TT - 1) + i];

    // Per-lane theta. Shared init across rows; evolves per-row.
    float w1a = W1[2 * lane + 0];   // W1[lane][0] (t column)
    float w1b = W1[2 * lane + 1];   // W1[lane][1] (y column)
    float b1v = b1[lane];
    float b2v = b2[lane];
    float w3v = W3[lane];           // W3[0][lane]
    float b3v = b3[0];

    float w2r[HH];  // W2[lane][j]  (row of W2)
    float w2c[HH];  // W2[i][lane]  (column of W2)
#pragma unroll
    for (int j = 0; j < HH; ++j) w2r[j] = W2[lane * HH + j];
#pragma unroll
    for (int i = 0; i < HH; ++i) w2c[i] = W2[i * HH + lane];

    __syncthreads();

    float t_prev = s_ts[0];
    const float x0 = s_xs[0];
    float x_hat  = x0;
    float x_prev = x0;
    if (lane == 0) out[row * TT] = x0;

    const float4* h1v  = (const float4*)s_h1;
    const float4* dz2v = (const float4*)s_dz2;

    for (int t = 1; t < TT; ++t) {
        const float tc     = s_ts[t];
        const float x_true = s_xs[t];
        const int   m      = s_mask[t - 1];
        const float x_t    = m ? x_true : x_hat;   // teacher forcing

        for (int gs = 0; gs < NGS; ++gs) {
            // ---- forward at current theta: input (tc, x_prev), target x_t
            float z1 = fmaf(w1a, tc, fmaf(w1b, x_prev, b1v));
            float h1 = tanhf(z1);
            s_h1[lane] = h1;
            __syncthreads();

            float a0 = 0.f, a1 = 0.f, a2 = 0.f, a3 = 0.f;
#pragma unroll
            for (int k = 0; k < HH / 4; ++k) {
                float4 hv = h1v[k];                 // broadcast read
                a0 = fmaf(w2r[4 * k + 0], hv.x, a0);
                a1 = fmaf(w2r[4 * k + 1], hv.y, a1);
                a2 = fmaf(w2r[4 * k + 2], hv.z, a2);
                a3 = fmaf(w2r[4 * k + 3], hv.w, a3);
            }
            float z2 = ((a0 + a1) + (a2 + a3)) + b2v;
            float h2 = tanhf(z2);

            float p = w3v * h2;                     // head: pred = sum_i W3_i h2_i + b3
            p += __shfl_xor(p, 32); p += __shfl_xor(p, 16); p += __shfl_xor(p, 8);
            p += __shfl_xor(p, 4);  p += __shfl_xor(p, 2);  p += __shfl_xor(p, 1);
            const float pred  = p + b3v;
            const float dl    = 2.0f * (pred - x_t);            // dL/dpred
            const float dz2s  = dl * w3v * (1.0f - h2 * h2);    // uses OLD w3
            s_dz2[lane] = dz2s;

            // head + bias updates (gradients fully computed from old theta)
            w3v = fmaf(-LR * dl, h2, w3v);
            b3v -= LR * dl;
            b2v -= LR * dz2s;
            __syncthreads();

            // ---- dh1 = W2^T dz2 (old W2 cols), fused with w2c rank-1 update
            const float nlrh = -LR * h1;            // for w2c: -= lr*dz2_i*h1_lane
            float d0 = 0.f, d1 = 0.f, d2 = 0.f, d3 = 0.f;
#pragma unroll
            for (int k = 0; k < HH / 4; ++k) {
                float4 dzv = dz2v[k];               // broadcast read
                d0 = fmaf(w2c[4 * k + 0], dzv.x, d0);
                d1 = fmaf(w2c[4 * k + 1], dzv.y, d1);
                d2 = fmaf(w2c[4 * k + 2], dzv.z, d2);
                d3 = fmaf(w2c[4 * k + 3], dzv.w, d3);
                w2c[4 * k + 0] = fmaf(nlrh, dzv.x, w2c[4 * k + 0]);
                w2c[4 * k + 1] = fmaf(nlrh, dzv.y, w2c[4 * k + 1]);
                w2c[4 * k + 2] = fmaf(nlrh, dzv.z, w2c[4 * k + 2]);
                w2c[4 * k + 3] = fmaf(nlrh, dzv.w, w2c[4 * k + 3]);
            }
            const float dh1 = (d0 + d1) + (d2 + d3);
            const float dz1 = dh1 * (1.0f - h1 * h1);
            w1a = fmaf(-LR * dz1, tc, w1a);
            w1b = fmaf(-LR * dz1, x_prev, w1b);
            b1v -= LR * dz1;

            // ---- w2r rank-1 update: W2[lane][j] -= lr*dz2_lane*h1_j
            const float nlrdz = -LR * dz2s;
#pragma unroll
            for (int k = 0; k < HH / 4; ++k) {
                float4 hv = h1v[k];                 // h1 still valid in LDS
                w2r[4 * k + 0] = fmaf(nlrdz, hv.x, w2r[4 * k + 0]);
                w2r[4 * k + 1] = fmaf(nlrdz, hv.y, w2r[4 * k + 1]);
                w2r[4 * k + 2] = fmaf(nlrdz, hv.z, w2r[4 * k + 2]);
                w2r[4 * k + 3] = fmaf(nlrdz, hv.w, w2r[4 * k + 3]);
            }
            __syncthreads();
        }

        // ---- final forward with adapted theta: input (tc + (tc - t_prev), x_true)
        const float deltat = tc - t_prev;
        const float tin    = tc + deltat;
        float z1 = fmaf(w1a, tin, fmaf(w1b, x_true, b1v));
        float h1 = tanhf(z1);
        s_h1[lane] = h1;
        __syncthreads();

        float a0 = 0.f, a1 = 0.f, a2 = 0.f, a3 = 0.f;
#pragma unroll
        for (int k = 0; k < HH / 4; ++k) {
            float4 hv = h1v[k];
            a0 = fmaf(w2r[4 * k + 0], hv.x, a0);
            a1 = fmaf(w2r[4 * k + 1], hv.y, a1);
            a2 = fmaf(w2r[4 * k + 2], hv.z, a2);
            a3 = fmaf(w2r[4 * k + 3], hv.w, a3);
        }
        float z2 = ((a0 + a1) + (a2 + a3)) + b2v;
        float h2 = tanhf(z2);
        float p = w3v * h2;
        p += __shfl_xor(p, 32); p += __shfl_xor(p, 16); p += __shfl_xor(p, 8);
        p += __shfl_xor(p, 4);  p += __shfl_xor(p, 2);  p += __shfl_xor(p, 1);
        x_hat = p + b3v;

        if (lane == 0) out[row * TT + t] = x_hat;
        t_prev = tc;
        x_prev = x_true;
        __syncthreads();  // protect s_h1 WAR into next timestep
    }
}

extern "C" void kernel_launch(void* const* d_in, const int* in_sizes, int n_in,
                              void* d_out, int out_size, void* d_ws, size_t ws_size,
                              hipStream_t stream) {
    const float* ts   = (const float*)d_in[0];
    const float* xs   = (const float*)d_in[1];
    const int*   mask = (const int*)d_in[2];
    const float* W1   = (const float*)d_in[3];
    const float* b1   = (const float*)d_in[4];
    const float* W2   = (const float*)d_in[5];
    const float* b2   = (const float*)d_in[6];
    const float* W3   = (const float*)d_in[7];
    const float* b3   = (const float*)d_in[8];
    float* out = (float*)d_out;

    const int B = in_sizes[1] / TT;  // 2048
    dim3 grid(B), block(HH);
    hipLaunchKernelGGL(ttt_kernel, grid, block, 0, stream,
                       ts, xs, mask, W1, b1, W2, b2, W3, b3, out);
}